// Round 16
// baseline (345.715 us; speedup 1.0000x reference)
//
#include <hip/hip_runtime.h>
#include <math.h>

// JointAttention B=64, N+1=16, T=256, H=128, TEMP=1
// R16 = R13/R15 + masked-tile slimming in passX: fully-masked tiles (37.5%)
// now also skip Klo staging and use a 2-MFMA QK (q_hi*k_hi + q_lo*k_hi) --
// they only feed ssq, where k-rounding noise is zero-mean and ~1e-4 rel.
// Live tiles byte-identical. Barriers uniform (live is block-uniform).

constexpr int BB   = 64;
constexpr int TT   = 256;
constexpr int HH   = 128;
constexpr int KEYS = 4096;
constexpr int LDK  = 136;   // bf16 row pad (x-tile, K-tile)
constexpr int LDV  = 72;    // bf16 Vt/As pad
constexpr float SOFF = 20.f;  // fixed softmax offset

typedef __attribute__((ext_vector_type(8)))  __bf16 bf16x8;
typedef __attribute__((ext_vector_type(16))) float  f32x16;
typedef __attribute__((ext_vector_type(4)))  float  f32x4;
typedef __attribute__((ext_vector_type(4)))  unsigned u32x4;
typedef unsigned short ushort_t;

__device__ __forceinline__ float4 ld4(const float* p) {
  return *reinterpret_cast<const float4*>(p);
}
__device__ __forceinline__ ushort_t f2bf(float x) {
  union { __bf16 b; ushort_t u; } c; c.b = (__bf16)x; return c.u;
}
__device__ __forceinline__ float bf2f(ushort_t h) {
  return __uint_as_float(((unsigned)h) << 16);
}
__device__ __forceinline__ void splitf(float x, ushort_t& h, ushort_t& l) {
  h = f2bf(x);
  l = f2bf(x - bf2f(h));
}
__device__ __forceinline__ f32x16 zero16() {
  f32x16 z;
  #pragma unroll
  for (int i = 0; i < 16; ++i) z[i] = 0.f;
  return z;
}
__device__ __forceinline__ f32x16 mfma3(bf16x8 ahi, bf16x8 alo,
                                        bf16x8 bhi, bf16x8 blo, f32x16 c) {
  c = __builtin_amdgcn_mfma_f32_32x32x16_bf16(ahi, bhi, c, 0, 0, 0);
  c = __builtin_amdgcn_mfma_f32_32x32x16_bf16(ahi, blo, c, 0, 0, 0);
  c = __builtin_amdgcn_mfma_f32_32x32x16_bf16(alo, bhi, c, 0, 0, 0);
  return c;
}

// ------------- pre-split weights into hi/lo bf16 planes --------------------
__global__ __launch_bounds__(256) void prep_w_kernel(
    const float* __restrict__ Wq, const float* __restrict__ Wk,
    const float* __restrict__ Wv,
    ushort_t* __restrict__ wqh, ushort_t* __restrict__ wql,
    ushort_t* __restrict__ wkh, ushort_t* __restrict__ wkl,
    ushort_t* __restrict__ wvh, ushort_t* __restrict__ wvl)
{
  int i = blockIdx.x * 256 + threadIdx.x;
  if (i >= HH * HH) return;
  ushort_t h, l;
  splitf(Wq[i], h, l); wqh[i] = h; wql[i] = l;
  splitf(Wk[i], h, l); wkh[i] = h; wkl[i] = l;
  splitf(Wv[i], h, l); wvh[i] = h; wvl[i] = l;
}

// ------------- MFMA projection: y = x @ W^T + b (split-bf16) --------------
// 64 rows/block, 256 thr (4 waves). Wave w owns j in [32w, 32w+32).
template<bool DOV>
__global__ __launch_bounds__(256, 4) void proj_kernel(
    const float* __restrict__ node, const float* __restrict__ neigh,
    const ushort_t* __restrict__ W1h, const ushort_t* __restrict__ W1l,
    const float* __restrict__ b1,
    const ushort_t* __restrict__ WVh, const ushort_t* __restrict__ WVl,
    const float* __restrict__ bV,
    ushort_t* __restrict__ yh, ushort_t* __restrict__ yl,
    ushort_t* __restrict__ v_t, int mode)
{
  __shared__ ushort_t xh[64 * LDK];
  __shared__ ushort_t xl[64 * LDK];
  const int tid = threadIdx.x;
  const long r0 = (long)blockIdx.x * 64;

  #pragma unroll
  for (int i = 0; i < 8; ++i) {
    int slot = tid + 256 * i;              // 0..2047
    int row = slot >> 5, h0 = (slot & 31) << 2;
    long r = r0 + row;
    const float* src;
    if (mode == 0) {
      src = node + r * HH;
    } else {
      long bb = r >> 12;
      int  n  = (int)((r >> 8) & 15);
      int  t  = (int)(r & 255);
      src = (n == 0) ? (node + (bb * TT + t) * HH)
                     : (neigh + ((bb * 15 + (n - 1)) * (long)TT + t) * HH);
    }
    float4 xv = ld4(src + h0);
    ushort_t h0h, h0l, h1h, h1l, h2h, h2l, h3h, h3l;
    splitf(xv.x, h0h, h0l); splitf(xv.y, h1h, h1l);
    splitf(xv.z, h2h, h2l); splitf(xv.w, h3h, h3l);
    *reinterpret_cast<uint2*>(&xh[row * LDK + h0]) =
        make_uint2((unsigned)h0h | ((unsigned)h1h << 16),
                   (unsigned)h2h | ((unsigned)h3h << 16));
    *reinterpret_cast<uint2*>(&xl[row * LDK + h0]) =
        make_uint2((unsigned)h0l | ((unsigned)h1l << 16),
                   (unsigned)h2l | ((unsigned)h3l << 16));
  }
  __syncthreads();

  const int l = tid & 63, w = tid >> 6, g = l >> 5, lane31 = l & 31;
  const int j = 32 * w + lane31;

  f32x16 accK[2];
  #pragma unroll
  for (int kt = 0; kt < 2; ++kt) accK[kt] = zero16();
  f32x16 accV[2];
  if constexpr (DOV) {
    #pragma unroll
    for (int kt = 0; kt < 2; ++kt) accV[kt] = zero16();
  }

  #pragma unroll
  for (int hs = 0; hs < 8; ++hs) {
    const int ho = 16 * hs + 8 * g;
    bf16x8 wh = *reinterpret_cast<const bf16x8*>(W1h + j * HH + ho);
    bf16x8 wl = *reinterpret_cast<const bf16x8*>(W1l + j * HH + ho);
    bf16x8 xhf[2], xlf[2];
    #pragma unroll
    for (int rt = 0; rt < 2; ++rt) {
      xhf[rt] = *reinterpret_cast<const bf16x8*>(&xh[(32 * rt + lane31) * LDK + ho]);
      xlf[rt] = *reinterpret_cast<const bf16x8*>(&xl[(32 * rt + lane31) * LDK + ho]);
    }
    #pragma unroll
    for (int rt = 0; rt < 2; ++rt)
      accK[rt] = mfma3(xhf[rt], xlf[rt], wh, wl, accK[rt]);
    if constexpr (DOV) {
      bf16x8 vh = *reinterpret_cast<const bf16x8*>(WVh + j * HH + ho);
      // V path: 2 MFMAs (drop w_lo terms, ~0.2% rel err << bf16 rounding)
      #pragma unroll
      for (int rt = 0; rt < 2; ++rt) {
        accV[rt] = __builtin_amdgcn_mfma_f32_32x32x16_bf16(vh, xhf[rt], accV[rt], 0, 0, 0);
        accV[rt] = __builtin_amdgcn_mfma_f32_32x32x16_bf16(vh, xlf[rt], accV[rt], 0, 0, 0);
      }
    }
  }

  const float bK = b1[j];
  #pragma unroll
  for (int kt = 0; kt < 2; ++kt) {
    #pragma unroll
    for (int reg = 0; reg < 16; ++reg) {
      int rm = (reg & 3) + 8 * (reg >> 2) + 4 * g;
      long r = r0 + 32 * kt + rm;
      ushort_t h, lo_;
      splitf(accK[kt][reg] + bK, h, lo_);
      yh[r * HH + j] = h;
      yl[r * HH + j] = lo_;
    }
  }
  if constexpr (DOV) {
    const int bidx = (int)(r0 >> 12);
    const int key0 = (int)(r0 & (KEYS - 1));
    float bvr[16];
    #pragma unroll
    for (int reg = 0; reg < 16; ++reg)
      bvr[reg] = bV[32 * w + (reg & 3) + 8 * (reg >> 2) + 4 * g];
    #pragma unroll
    for (int kt = 0; kt < 2; ++kt) {
      #pragma unroll
      for (int reg = 0; reg < 16; ++reg) {
        int rm = (reg & 3) + 8 * (reg >> 2) + 4 * g;
        int jrow = 32 * w + rm;
        v_t[((long)(bidx * HH + jrow)) * KEYS + key0 + 32 * kt + lane31] =
            f2bf(accV[kt][reg] + bvr[reg]);
      }
    }
  }
}

// ---------------- passX: QK + P(bf16) + PV + L + ssq (single sweep) --------
// grid 512: b(64) x tq(4) x ksb(2), 256 thr. Fully-masked tiles skip Klo
// staging, V staging, softmax/As/export/PV; their QK is 2-MFMA (hi-only K).
__global__ __launch_bounds__(256, 2) void passX_kernel(
    const ushort_t* __restrict__ q_hi, const ushort_t* __restrict__ q_lo,
    const ushort_t* __restrict__ k_hi, const ushort_t* __restrict__ k_lo,
    const ushort_t* __restrict__ v_t,
    ushort_t* __restrict__ P_out, float* __restrict__ l_part,
    float* __restrict__ ssq_part, float* __restrict__ opart)
{
  __shared__ ushort_t Khi[64 * LDK];
  __shared__ ushort_t Klo[64 * LDK];
  __shared__ ushort_t Vt[128 * LDV];
  __shared__ ushort_t As[64 * LDV];
  __shared__ float redS[4];
  const int tid = threadIdx.x, l = tid & 63, w = tid >> 6;
  const int g = (l >> 5) & 1, lane31 = l & 31;
  const int wt = w & 1, wk = w >> 1;
  const int p = blockIdx.x;
  const int xcd = p & 7, slot = p >> 3;
  const int pair = xcd * 16 + (slot >> 2);
  const int tq = slot & 3;
  const int b = pair >> 1, ksb = pair & 1;
  const int t0 = tq * 64;

  bf16x8 qhi[8], qlo[8];
  {
    const long qb = ((long)(b * TT + t0 + 32 * wt + lane31)) * HH;
    #pragma unroll
    for (int hs = 0; hs < 8; ++hs) {
      qhi[hs] = *reinterpret_cast<const bf16x8*>(q_hi + qb + 16 * hs + 8 * g);
      qlo[hs] = *reinterpret_cast<const bf16x8*>(q_lo + qb + 16 * hs + 8 * g);
    }
  }

  float lreg[16];
  #pragma unroll
  for (int r = 0; r < 16; ++r) lreg[r] = 0.f;
  float ssq = 0.f;
  f32x16 o0 = zero16(), o1 = zero16();

  for (int kt = 0; kt < 32; ++kt) {
    const int kb = ksb * 2048 + kt * 64;
    // tile's source-time base; fully masked iff st0 > t0+63 (block-uniform)
    const bool live = (kb & 255) <= (t0 | 63);

    __syncthreads();   // prev iter's readers done with Khi/Klo/Vt/As
    #pragma unroll
    for (int i = 0; i < 4; ++i) {
      int s2 = i * 256 + tid;
      int row = s2 >> 4, c0 = (s2 & 15) << 3;
      const long gsrc = ((long)(b * KEYS + kb + row)) * HH + c0;
      *reinterpret_cast<uint4*>(&Khi[row * LDK + c0]) =
          *reinterpret_cast<const uint4*>(k_hi + gsrc);
    }
    if (live) {
      #pragma unroll
      for (int i = 0; i < 4; ++i) {
        int s2 = i * 256 + tid;
        int row = s2 >> 4, c0 = (s2 & 15) << 3;
        const long gsrc = ((long)(b * KEYS + kb + row)) * HH + c0;
        *reinterpret_cast<uint4*>(&Klo[row * LDK + c0]) =
            *reinterpret_cast<const uint4*>(k_lo + gsrc);
      }
      #pragma unroll
      for (int i = 0; i < 4; ++i) {
        int s2 = i * 256 + tid;
        int hh = s2 >> 3, k0 = (s2 & 7) << 3;
        *reinterpret_cast<uint4*>(&Vt[hh * LDV + k0]) =
            *reinterpret_cast<const uint4*>(
                v_t + ((long)(b * HH + hh)) * KEYS + kb + k0);
      }
    }
    __syncthreads();

    if (live) {
      // full split-bf16 QK, two independent accumulator chains (ILP-2)
      __builtin_amdgcn_s_setprio(1);
      f32x16 accA = zero16(), accB = zero16();
      #pragma unroll
      for (int hp = 0; hp < 4; ++hp) {
        const int hoA = 16 * (2 * hp) + 8 * g;
        const int hoB = 16 * (2 * hp + 1) + 8 * g;
        bf16x8 khA = *reinterpret_cast<const bf16x8*>(
            &Khi[(32 * wk + lane31) * LDK + hoA]);
        bf16x8 klA = *reinterpret_cast<const bf16x8*>(
            &Klo[(32 * wk + lane31) * LDK + hoA]);
        bf16x8 khB = *reinterpret_cast<const bf16x8*>(
            &Khi[(32 * wk + lane31) * LDK + hoB]);
        bf16x8 klB = *reinterpret_cast<const bf16x8*>(
            &Klo[(32 * wk + lane31) * LDK + hoB]);
        accA = mfma3(qhi[2 * hp],     qlo[2 * hp],     khA, klA, accA);
        accB = mfma3(qhi[2 * hp + 1], qlo[2 * hp + 1], khB, klB, accB);
      }
      __builtin_amdgcn_s_setprio(0);

      const int key = kb + 32 * wk + lane31;
      const int st = key & 255;
      #pragma unroll
      for (int reg = 0; reg < 16; ++reg) {
        const int rl = 32 * wt + (reg & 3) + 8 * (reg >> 2) + 4 * g;
        const int tr = t0 + rl;
        float s = accA[reg] + accB[reg];
        ssq = fmaf(s, s, ssq);
        float pv_ = (st <= tr) ? __expf(s - SOFF) : 0.f;
        lreg[reg] += pv_;
        As[rl * LDV + 32 * wk + lane31] = f2bf(pv_);
      }
      __syncthreads();   // As visible

      // export P tile first: global stores drain under the PV MFMAs
      #pragma unroll
      for (int c = 0; c < 2; ++c) {
        int s3 = c * 256 + tid;
        int row = s3 >> 3, col = (s3 & 7) << 3;
        *reinterpret_cast<uint4*>(
            P_out + ((long)(b * TT + t0 + row)) * KEYS + kb + col) =
            *reinterpret_cast<const uint4*>(&As[row * LDV + col]);
      }

      __builtin_amdgcn_s_setprio(1);
      #pragma unroll
      for (int ksx = 0; ksx < 4; ++ksx) {
        const int ko = 16 * ksx + 8 * g;
        bf16x8 af = *reinterpret_cast<const bf16x8*>(
            &As[(32 * wt + lane31) * LDV + ko]);
        bf16x8 v0 = *reinterpret_cast<const bf16x8*>(
            &Vt[(64 * wk + lane31) * LDV + ko]);
        bf16x8 v1 = *reinterpret_cast<const bf16x8*>(
            &Vt[(64 * wk + 32 + lane31) * LDV + ko]);
        o0 = __builtin_amdgcn_mfma_f32_32x32x16_bf16(af, v0, o0, 0, 0, 0);
        o1 = __builtin_amdgcn_mfma_f32_32x32x16_bf16(af, v1, o1, 0, 0, 0);
      }
      __builtin_amdgcn_s_setprio(0);
    } else {
      // masked tile: ssq only. 2-MFMA QK (hi-only K; q stays split).
      __builtin_amdgcn_s_setprio(1);
      f32x16 accA = zero16(), accB = zero16();
      #pragma unroll
      for (int hp = 0; hp < 4; ++hp) {
        const int hoA = 16 * (2 * hp) + 8 * g;
        const int hoB = 16 * (2 * hp + 1) + 8 * g;
        bf16x8 khA = *reinterpret_cast<const bf16x8*>(
            &Khi[(32 * wk + lane31) * LDK + hoA]);
        bf16x8 khB = *reinterpret_cast<const bf16x8*>(
            &Khi[(32 * wk + lane31) * LDK + hoB]);
        accA = __builtin_amdgcn_mfma_f32_32x32x16_bf16(qhi[2 * hp], khA, accA, 0, 0, 0);
        accA = __builtin_amdgcn_mfma_f32_32x32x16_bf16(qlo[2 * hp], khA, accA, 0, 0, 0);
        accB = __builtin_amdgcn_mfma_f32_32x32x16_bf16(qhi[2 * hp + 1], khB, accB, 0, 0, 0);
        accB = __builtin_amdgcn_mfma_f32_32x32x16_bf16(qlo[2 * hp + 1], khB, accB, 0, 0, 0);
      }
      __builtin_amdgcn_s_setprio(0);
      #pragma unroll
      for (int reg = 0; reg < 16; ++reg) {
        float s = accA[reg] + accB[reg];
        ssq = fmaf(s, s, ssq);
      }
    }
  }

  // L: sum over the 32 lane31 key-columns
  #pragma unroll
  for (int reg = 0; reg < 16; ++reg) {
    #pragma unroll
    for (int off = 1; off < 32; off <<= 1)
      lreg[reg] += __shfl_xor(lreg[reg], off);
  }
  if (lane31 == 0) {
    const int slotL = ksb * 2 + wk;
    #pragma unroll
    for (int reg = 0; reg < 16; ++reg) {
      const int tr = t0 + 32 * wt + (reg & 3) + 8 * (reg >> 2) + 4 * g;
      l_part[slotL * (BB * TT) + b * TT + tr] = lreg[reg];
    }
  }

  // ssq reduce
  #pragma unroll
  for (int off = 1; off < 64; off <<= 1) ssq += __shfl_xor(ssq, off);
  if (l == 0) redS[w] = ssq;
  __syncthreads();
  if (tid == 0)
    ssq_part[b * 8 + tq * 2 + ksb] = redS[0] + redS[1] + redS[2] + redS[3];

  #pragma unroll
  for (int reg = 0; reg < 16; ++reg) {
    const int tr = t0 + 32 * wt + (reg & 3) + 8 * (reg >> 2) + 4 * g;
    long base = (long)ksb * (BB * TT * HH) + ((long)(b * TT + tr)) * HH + 64 * wk;
    opart[base + lane31]      = o0[reg];
    opart[base + 32 + lane31] = o1[reg];
  }
}

// ---------------- passY: A = P * (1/L); masked chunks -> zeros -------------
__global__ __launch_bounds__(256) void passY_kernel(
    const ushort_t* __restrict__ P_in, const float* __restrict__ l_part,
    float* __restrict__ A_out)
{
  const long total = (long)BB * TT * KEYS / 8;   // 8-element chunks
  for (long u = (long)blockIdx.x * 256 + threadIdx.x; u < total;
       u += (long)gridDim.x * 256) {
    const int row = (int)(u >> 9);               // b*TT + t
    const int t = row & 255;
    const int s0 = ((int)(u & 511) << 3) & 255;  // chunk's source-time base
    f32x4 a0, a1;
    if (s0 > t) {                                // fully masked chunk
      a0 = (f32x4){0.f, 0.f, 0.f, 0.f};
      a1 = a0;
    } else {
      const float L = l_part[row] + l_part[BB * TT + row] +
                      l_part[2 * BB * TT + row] + l_part[3 * BB * TT + row];
      const float s = 1.0f / L;
      u32x4 pv = __builtin_nontemporal_load(
          reinterpret_cast<const u32x4*>(P_in + u * 8));
      a0.x = bf2f((ushort_t)(pv.x & 0xffff)) * s;
      a0.y = bf2f((ushort_t)(pv.x >> 16)) * s;
      a0.z = bf2f((ushort_t)(pv.y & 0xffff)) * s;
      a0.w = bf2f((ushort_t)(pv.y >> 16)) * s;
      a1.x = bf2f((ushort_t)(pv.z & 0xffff)) * s;
      a1.y = bf2f((ushort_t)(pv.z >> 16)) * s;
      a1.z = bf2f((ushort_t)(pv.w & 0xffff)) * s;
      a1.w = bf2f((ushort_t)(pv.w >> 16)) * s;
    }
    __builtin_nontemporal_store(a0, reinterpret_cast<f32x4*>(A_out + u * 8));
    __builtin_nontemporal_store(a1, reinterpret_cast<f32x4*>(A_out + u * 8 + 4));
  }
}

// ---------------- out = (opart0 + opart1) * (1/L) --------------------------
__global__ void reduce_out_kernel(const float* __restrict__ opart,
                                  const float* __restrict__ l_part,
                                  float* __restrict__ out)
{
  int i = blockIdx.x * 256 + threadIdx.x;
  const int n4 = BB * TT * HH / 4;
  if (i >= n4) return;
  const int row = i >> 5;                        // 32 float4 per row
  const float L = l_part[row] + l_part[BB * TT + row] +
                  l_part[2 * BB * TT + row] + l_part[3 * BB * TT + row];
  const float s = 1.0f / L;
  const float4* p0 = reinterpret_cast<const float4*>(opart);
  const float4* p1 = reinterpret_cast<const float4*>(opart + (long)BB * TT * HH);
  float4 a = p0[i], c = p1[i];
  a.x = (a.x + c.x) * s;
  a.y = (a.y + c.y) * s;
  a.z = (a.z + c.z) * s;
  a.w = (a.w + c.w) * s;
  *reinterpret_cast<float4*>(out + 4 * (long)i) = a;
}

__global__ void finalize_kernel(const float* __restrict__ ssq_part,
                                float* __restrict__ S_norm)
{
  int b = threadIdx.x;
  if (b < BB) {
    float s = 0.f;
    #pragma unroll
    for (int i = 0; i < 8; ++i) s += ssq_part[b * 8 + i];
    S_norm[b] = sqrtf(s);
  }
}

extern "C" void kernel_launch(void* const* d_in, const int* in_sizes, int n_in,
                              void* d_out, int out_size, void* d_ws, size_t ws_size,
                              hipStream_t stream)
{
  const float* node  = (const float*)d_in[0];
  const float* neigh = (const float*)d_in[1];
  const float* Wq = (const float*)d_in[4];
  const float* bq = (const float*)d_in[5];
  const float* Wk = (const float*)d_in[6];
  const float* bk = (const float*)d_in[7];
  const float* Wv = (const float*)d_in[8];
  const float* bv = (const float*)d_in[9];

  float* out    = (float*)d_out;
  float* A_out  = out + (long)BB * TT * HH;
  float* S_norm = A_out + (long)BB * TT * KEYS;

  ushort_t* q_hi = (ushort_t*)d_ws;                      // B*T*H
  ushort_t* q_lo = q_hi + (long)BB * TT * HH;
  ushort_t* k_hi = q_lo + (long)BB * TT * HH;            // B*KEYS*H
  ushort_t* k_lo = k_hi + (long)BB * KEYS * HH;
  ushort_t* v_t  = k_lo + (long)BB * KEYS * HH;          // B*H*KEYS
  ushort_t* wqh  = v_t + (long)BB * HH * KEYS;           // H*H x6
  ushort_t* wql  = wqh + HH * HH;
  ushort_t* wkh  = wql + HH * HH;
  ushort_t* wkl  = wkh + HH * HH;
  ushort_t* wvh  = wkl + HH * HH;
  ushort_t* wvl  = wvh + HH * HH;
  ushort_t* P_ws = wvl + HH * HH;                        // B*T*KEYS bf16
  float* l_part  = (float*)(P_ws + (long)BB * TT * KEYS);// 4*B*T
  float* ssq_part = l_part + 4 * BB * TT;                // 512
  float* opart   = ssq_part + 512;                       // 2*B*T*H

  prep_w_kernel<<<dim3((HH * HH + 255) / 256), dim3(256), 0, stream>>>(
      Wq, Wk, Wv, wqh, wql, wkh, wkl, wvh, wvl);
  proj_kernel<false><<<dim3(BB * TT / 64), dim3(256), 0, stream>>>(
      node, neigh, wqh, wql, bq, wvh, wvl, bv, q_hi, q_lo, v_t, 0);
  proj_kernel<true><<<dim3(BB * KEYS / 64), dim3(256), 0, stream>>>(
      node, neigh, wkh, wkl, bk, wvh, wvl, bv, k_hi, k_lo, v_t, 1);
  passX_kernel<<<dim3(BB * 8), dim3(256), 0, stream>>>(
      q_hi, q_lo, k_hi, k_lo, v_t, P_ws, l_part, ssq_part, opart);
  passY_kernel<<<dim3(4096), dim3(256), 0, stream>>>(P_ws, l_part, A_out);
  reduce_out_kernel<<<dim3((BB * TT * HH / 4 + 255) / 256), dim3(256), 0, stream>>>(
      opart, l_part, out);
  finalize_kernel<<<dim3(1), dim3(64), 0, stream>>>(ssq_part, S_norm);
}

// Round 17
// 340.209 us; speedup vs baseline: 1.0162x; 1.0162x over previous
//
#include <hip/hip_runtime.h>
#include <math.h>

// JointAttention B=64, N+1=16, T=256, H=128, TEMP=1
// R17 = exact revert to R15/R13 (best measured: 340.8 us).
// R16's masked-tile slimming (-30MB fetch) was net-negative: the live-gated
// Klo staging split the fused 12-load staging burst and live-path codegen
// regressed. Final structure: split-bf16 MFMA projections (fused K+V,
// V transposed), single-sweep passX (QK + fixed-offset exp P(bf16) + PV + L
// + ssq, causal tile-skip), streaming passY (A = P/L), small reductions.

constexpr int BB   = 64;
constexpr int TT   = 256;
constexpr int HH   = 128;
constexpr int KEYS = 4096;
constexpr int LDK  = 136;   // bf16 row pad (x-tile, K-tile)
constexpr int LDV  = 72;    // bf16 Vt/As pad
constexpr float SOFF = 20.f;  // fixed softmax offset

typedef __attribute__((ext_vector_type(8)))  __bf16 bf16x8;
typedef __attribute__((ext_vector_type(16))) float  f32x16;
typedef __attribute__((ext_vector_type(4)))  float  f32x4;
typedef __attribute__((ext_vector_type(4)))  unsigned u32x4;
typedef unsigned short ushort_t;

__device__ __forceinline__ float4 ld4(const float* p) {
  return *reinterpret_cast<const float4*>(p);
}
__device__ __forceinline__ ushort_t f2bf(float x) {
  union { __bf16 b; ushort_t u; } c; c.b = (__bf16)x; return c.u;
}
__device__ __forceinline__ float bf2f(ushort_t h) {
  return __uint_as_float(((unsigned)h) << 16);
}
__device__ __forceinline__ void splitf(float x, ushort_t& h, ushort_t& l) {
  h = f2bf(x);
  l = f2bf(x - bf2f(h));
}
__device__ __forceinline__ f32x16 zero16() {
  f32x16 z;
  #pragma unroll
  for (int i = 0; i < 16; ++i) z[i] = 0.f;
  return z;
}
__device__ __forceinline__ f32x16 mfma3(bf16x8 ahi, bf16x8 alo,
                                        bf16x8 bhi, bf16x8 blo, f32x16 c) {
  c = __builtin_amdgcn_mfma_f32_32x32x16_bf16(ahi, bhi, c, 0, 0, 0);
  c = __builtin_amdgcn_mfma_f32_32x32x16_bf16(ahi, blo, c, 0, 0, 0);
  c = __builtin_amdgcn_mfma_f32_32x32x16_bf16(alo, bhi, c, 0, 0, 0);
  return c;
}

// ------------- pre-split weights into hi/lo bf16 planes --------------------
__global__ __launch_bounds__(256) void prep_w_kernel(
    const float* __restrict__ Wq, const float* __restrict__ Wk,
    const float* __restrict__ Wv,
    ushort_t* __restrict__ wqh, ushort_t* __restrict__ wql,
    ushort_t* __restrict__ wkh, ushort_t* __restrict__ wkl,
    ushort_t* __restrict__ wvh, ushort_t* __restrict__ wvl)
{
  int i = blockIdx.x * 256 + threadIdx.x;
  if (i >= HH * HH) return;
  ushort_t h, l;
  splitf(Wq[i], h, l); wqh[i] = h; wql[i] = l;
  splitf(Wk[i], h, l); wkh[i] = h; wkl[i] = l;
  splitf(Wv[i], h, l); wvh[i] = h; wvl[i] = l;
}

// ------------- MFMA projection: y = x @ W^T + b (split-bf16) --------------
// 64 rows/block, 256 thr (4 waves). Wave w owns j in [32w, 32w+32).
template<bool DOV>
__global__ __launch_bounds__(256, 4) void proj_kernel(
    const float* __restrict__ node, const float* __restrict__ neigh,
    const ushort_t* __restrict__ W1h, const ushort_t* __restrict__ W1l,
    const float* __restrict__ b1,
    const ushort_t* __restrict__ WVh, const ushort_t* __restrict__ WVl,
    const float* __restrict__ bV,
    ushort_t* __restrict__ yh, ushort_t* __restrict__ yl,
    ushort_t* __restrict__ v_t, int mode)
{
  __shared__ ushort_t xh[64 * LDK];
  __shared__ ushort_t xl[64 * LDK];
  const int tid = threadIdx.x;
  const long r0 = (long)blockIdx.x * 64;

  #pragma unroll
  for (int i = 0; i < 8; ++i) {
    int slot = tid + 256 * i;              // 0..2047
    int row = slot >> 5, h0 = (slot & 31) << 2;
    long r = r0 + row;
    const float* src;
    if (mode == 0) {
      src = node + r * HH;
    } else {
      long bb = r >> 12;
      int  n  = (int)((r >> 8) & 15);
      int  t  = (int)(r & 255);
      src = (n == 0) ? (node + (bb * TT + t) * HH)
                     : (neigh + ((bb * 15 + (n - 1)) * (long)TT + t) * HH);
    }
    float4 xv = ld4(src + h0);
    ushort_t h0h, h0l, h1h, h1l, h2h, h2l, h3h, h3l;
    splitf(xv.x, h0h, h0l); splitf(xv.y, h1h, h1l);
    splitf(xv.z, h2h, h2l); splitf(xv.w, h3h, h3l);
    *reinterpret_cast<uint2*>(&xh[row * LDK + h0]) =
        make_uint2((unsigned)h0h | ((unsigned)h1h << 16),
                   (unsigned)h2h | ((unsigned)h3h << 16));
    *reinterpret_cast<uint2*>(&xl[row * LDK + h0]) =
        make_uint2((unsigned)h0l | ((unsigned)h1l << 16),
                   (unsigned)h2l | ((unsigned)h3l << 16));
  }
  __syncthreads();

  const int l = tid & 63, w = tid >> 6, g = l >> 5, lane31 = l & 31;
  const int j = 32 * w + lane31;

  f32x16 accK[2];
  #pragma unroll
  for (int kt = 0; kt < 2; ++kt) accK[kt] = zero16();
  f32x16 accV[2];
  if constexpr (DOV) {
    #pragma unroll
    for (int kt = 0; kt < 2; ++kt) accV[kt] = zero16();
  }

  #pragma unroll
  for (int hs = 0; hs < 8; ++hs) {
    const int ho = 16 * hs + 8 * g;
    bf16x8 wh = *reinterpret_cast<const bf16x8*>(W1h + j * HH + ho);
    bf16x8 wl = *reinterpret_cast<const bf16x8*>(W1l + j * HH + ho);
    bf16x8 xhf[2], xlf[2];
    #pragma unroll
    for (int rt = 0; rt < 2; ++rt) {
      xhf[rt] = *reinterpret_cast<const bf16x8*>(&xh[(32 * rt + lane31) * LDK + ho]);
      xlf[rt] = *reinterpret_cast<const bf16x8*>(&xl[(32 * rt + lane31) * LDK + ho]);
    }
    #pragma unroll
    for (int rt = 0; rt < 2; ++rt)
      accK[rt] = mfma3(xhf[rt], xlf[rt], wh, wl, accK[rt]);
    if constexpr (DOV) {
      bf16x8 vh = *reinterpret_cast<const bf16x8*>(WVh + j * HH + ho);
      // V path: 2 MFMAs (drop w_lo terms, ~0.2% rel err << bf16 rounding)
      #pragma unroll
      for (int rt = 0; rt < 2; ++rt) {
        accV[rt] = __builtin_amdgcn_mfma_f32_32x32x16_bf16(vh, xhf[rt], accV[rt], 0, 0, 0);
        accV[rt] = __builtin_amdgcn_mfma_f32_32x32x16_bf16(vh, xlf[rt], accV[rt], 0, 0, 0);
      }
    }
  }

  const float bK = b1[j];
  #pragma unroll
  for (int kt = 0; kt < 2; ++kt) {
    #pragma unroll
    for (int reg = 0; reg < 16; ++reg) {
      int rm = (reg & 3) + 8 * (reg >> 2) + 4 * g;
      long r = r0 + 32 * kt + rm;
      ushort_t h, lo_;
      splitf(accK[kt][reg] + bK, h, lo_);
      yh[r * HH + j] = h;
      yl[r * HH + j] = lo_;
    }
  }
  if constexpr (DOV) {
    const int bidx = (int)(r0 >> 12);
    const int key0 = (int)(r0 & (KEYS - 1));
    float bvr[16];
    #pragma unroll
    for (int reg = 0; reg < 16; ++reg)
      bvr[reg] = bV[32 * w + (reg & 3) + 8 * (reg >> 2) + 4 * g];
    #pragma unroll
    for (int kt = 0; kt < 2; ++kt) {
      #pragma unroll
      for (int reg = 0; reg < 16; ++reg) {
        int rm = (reg & 3) + 8 * (reg >> 2) + 4 * g;
        int jrow = 32 * w + rm;
        v_t[((long)(bidx * HH + jrow)) * KEYS + key0 + 32 * kt + lane31] =
            f2bf(accV[kt][reg] + bvr[reg]);
      }
    }
  }
}

// ---------------- passX: QK + P(bf16) + PV + L + ssq (single sweep) --------
// grid 512: b(64) x tq(4) x ksb(2), 256 thr. Fully-masked tiles skip the
// softmax/As/export/PV phase (block-uniform). QK+ssq always run.
__global__ __launch_bounds__(256, 2) void passX_kernel(
    const ushort_t* __restrict__ q_hi, const ushort_t* __restrict__ q_lo,
    const ushort_t* __restrict__ k_hi, const ushort_t* __restrict__ k_lo,
    const ushort_t* __restrict__ v_t,
    ushort_t* __restrict__ P_out, float* __restrict__ l_part,
    float* __restrict__ ssq_part, float* __restrict__ opart)
{
  __shared__ ushort_t Khi[64 * LDK];
  __shared__ ushort_t Klo[64 * LDK];
  __shared__ ushort_t Vt[128 * LDV];
  __shared__ ushort_t As[64 * LDV];
  __shared__ float redS[4];
  const int tid = threadIdx.x, l = tid & 63, w = tid >> 6;
  const int g = (l >> 5) & 1, lane31 = l & 31;
  const int wt = w & 1, wk = w >> 1;
  const int p = blockIdx.x;
  const int xcd = p & 7, slot = p >> 3;
  const int pair = xcd * 16 + (slot >> 2);
  const int tq = slot & 3;
  const int b = pair >> 1, ksb = pair & 1;
  const int t0 = tq * 64;

  bf16x8 qhi[8], qlo[8];
  {
    const long qb = ((long)(b * TT + t0 + 32 * wt + lane31)) * HH;
    #pragma unroll
    for (int hs = 0; hs < 8; ++hs) {
      qhi[hs] = *reinterpret_cast<const bf16x8*>(q_hi + qb + 16 * hs + 8 * g);
      qlo[hs] = *reinterpret_cast<const bf16x8*>(q_lo + qb + 16 * hs + 8 * g);
    }
  }

  float lreg[16];
  #pragma unroll
  for (int r = 0; r < 16; ++r) lreg[r] = 0.f;
  float ssq = 0.f;
  f32x16 o0 = zero16(), o1 = zero16();

  for (int kt = 0; kt < 32; ++kt) {
    const int kb = ksb * 2048 + kt * 64;
    // tile's source-time base; fully masked iff st0 > t0+63 (block-uniform)
    const bool live = (kb & 255) <= (t0 | 63);

    __syncthreads();   // prev iter's readers done with Khi/Klo/Vt/As
    #pragma unroll
    for (int i = 0; i < 4; ++i) {
      int s2 = i * 256 + tid;
      int row = s2 >> 4, c0 = (s2 & 15) << 3;
      const long gsrc = ((long)(b * KEYS + kb + row)) * HH + c0;
      *reinterpret_cast<uint4*>(&Khi[row * LDK + c0]) =
          *reinterpret_cast<const uint4*>(k_hi + gsrc);
      *reinterpret_cast<uint4*>(&Klo[row * LDK + c0]) =
          *reinterpret_cast<const uint4*>(k_lo + gsrc);
    }
    if (live) {
      #pragma unroll
      for (int i = 0; i < 4; ++i) {
        int s2 = i * 256 + tid;
        int hh = s2 >> 3, k0 = (s2 & 7) << 3;
        *reinterpret_cast<uint4*>(&Vt[hh * LDV + k0]) =
            *reinterpret_cast<const uint4*>(
                v_t + ((long)(b * HH + hh)) * KEYS + kb + k0);
      }
    }
    __syncthreads();

    // QK with two independent accumulator chains (ILP-2); always (ssq!)
    __builtin_amdgcn_s_setprio(1);
    f32x16 accA = zero16(), accB = zero16();
    #pragma unroll
    for (int hp = 0; hp < 4; ++hp) {
      const int hoA = 16 * (2 * hp) + 8 * g;
      const int hoB = 16 * (2 * hp + 1) + 8 * g;
      bf16x8 khA = *reinterpret_cast<const bf16x8*>(
          &Khi[(32 * wk + lane31) * LDK + hoA]);
      bf16x8 klA = *reinterpret_cast<const bf16x8*>(
          &Klo[(32 * wk + lane31) * LDK + hoA]);
      bf16x8 khB = *reinterpret_cast<const bf16x8*>(
          &Khi[(32 * wk + lane31) * LDK + hoB]);
      bf16x8 klB = *reinterpret_cast<const bf16x8*>(
          &Klo[(32 * wk + lane31) * LDK + hoB]);
      accA = mfma3(qhi[2 * hp],     qlo[2 * hp],     khA, klA, accA);
      accB = mfma3(qhi[2 * hp + 1], qlo[2 * hp + 1], khB, klB, accB);
    }
    __builtin_amdgcn_s_setprio(0);

    if (live) {
      const int key = kb + 32 * wk + lane31;
      const int st = key & 255;
      #pragma unroll
      for (int reg = 0; reg < 16; ++reg) {
        const int rl = 32 * wt + (reg & 3) + 8 * (reg >> 2) + 4 * g;
        const int tr = t0 + rl;
        float s = accA[reg] + accB[reg];
        ssq = fmaf(s, s, ssq);
        float pv_ = (st <= tr) ? __expf(s - SOFF) : 0.f;
        lreg[reg] += pv_;
        As[rl * LDV + 32 * wk + lane31] = f2bf(pv_);
      }
      __syncthreads();   // As visible

      // export P tile first: global stores drain under the PV MFMAs
      #pragma unroll
      for (int c = 0; c < 2; ++c) {
        int s3 = c * 256 + tid;
        int row = s3 >> 3, col = (s3 & 7) << 3;
        *reinterpret_cast<uint4*>(
            P_out + ((long)(b * TT + t0 + row)) * KEYS + kb + col) =
            *reinterpret_cast<const uint4*>(&As[row * LDV + col]);
      }

      __builtin_amdgcn_s_setprio(1);
      #pragma unroll
      for (int ksx = 0; ksx < 4; ++ksx) {
        const int ko = 16 * ksx + 8 * g;
        bf16x8 af = *reinterpret_cast<const bf16x8*>(
            &As[(32 * wt + lane31) * LDV + ko]);
        bf16x8 v0 = *reinterpret_cast<const bf16x8*>(
            &Vt[(64 * wk + lane31) * LDV + ko]);
        bf16x8 v1 = *reinterpret_cast<const bf16x8*>(
            &Vt[(64 * wk + 32 + lane31) * LDV + ko]);
        o0 = __builtin_amdgcn_mfma_f32_32x32x16_bf16(af, v0, o0, 0, 0, 0);
        o1 = __builtin_amdgcn_mfma_f32_32x32x16_bf16(af, v1, o1, 0, 0, 0);
      }
      __builtin_amdgcn_s_setprio(0);
    } else {
      // masked tile: only ssq needed from the scores
      #pragma unroll
      for (int reg = 0; reg < 16; ++reg) {
        float s = accA[reg] + accB[reg];
        ssq = fmaf(s, s, ssq);
      }
    }
  }

  // L: sum over the 32 lane31 key-columns
  #pragma unroll
  for (int reg = 0; reg < 16; ++reg) {
    #pragma unroll
    for (int off = 1; off < 32; off <<= 1)
      lreg[reg] += __shfl_xor(lreg[reg], off);
  }
  if (lane31 == 0) {
    const int slotL = ksb * 2 + wk;
    #pragma unroll
    for (int reg = 0; reg < 16; ++reg) {
      const int tr = t0 + 32 * wt + (reg & 3) + 8 * (reg >> 2) + 4 * g;
      l_part[slotL * (BB * TT) + b * TT + tr] = lreg[reg];
    }
  }

  // ssq reduce
  #pragma unroll
  for (int off = 1; off < 64; off <<= 1) ssq += __shfl_xor(ssq, off);
  if (l == 0) redS[w] = ssq;
  __syncthreads();
  if (tid == 0)
    ssq_part[b * 8 + tq * 2 + ksb] = redS[0] + redS[1] + redS[2] + redS[3];

  #pragma unroll
  for (int reg = 0; reg < 16; ++reg) {
    const int tr = t0 + 32 * wt + (reg & 3) + 8 * (reg >> 2) + 4 * g;
    long base = (long)ksb * (BB * TT * HH) + ((long)(b * TT + tr)) * HH + 64 * wk;
    opart[base + lane31]      = o0[reg];
    opart[base + 32 + lane31] = o1[reg];
  }
}

// ---------------- passY: A = P * (1/L); masked chunks -> zeros -------------
__global__ __launch_bounds__(256) void passY_kernel(
    const ushort_t* __restrict__ P_in, const float* __restrict__ l_part,
    float* __restrict__ A_out)
{
  const long total = (long)BB * TT * KEYS / 8;   // 8-element chunks
  for (long u = (long)blockIdx.x * 256 + threadIdx.x; u < total;
       u += (long)gridDim.x * 256) {
    const int row = (int)(u >> 9);               // b*TT + t
    const int t = row & 255;
    const int s0 = ((int)(u & 511) << 3) & 255;  // chunk's source-time base
    f32x4 a0, a1;
    if (s0 > t) {                                // fully masked chunk
      a0 = (f32x4){0.f, 0.f, 0.f, 0.f};
      a1 = a0;
    } else {
      const float L = l_part[row] + l_part[BB * TT + row] +
                      l_part[2 * BB * TT + row] + l_part[3 * BB * TT + row];
      const float s = 1.0f / L;
      u32x4 pv = __builtin_nontemporal_load(
          reinterpret_cast<const u32x4*>(P_in + u * 8));
      a0.x = bf2f((ushort_t)(pv.x & 0xffff)) * s;
      a0.y = bf2f((ushort_t)(pv.x >> 16)) * s;
      a0.z = bf2f((ushort_t)(pv.y & 0xffff)) * s;
      a0.w = bf2f((ushort_t)(pv.y >> 16)) * s;
      a1.x = bf2f((ushort_t)(pv.z & 0xffff)) * s;
      a1.y = bf2f((ushort_t)(pv.z >> 16)) * s;
      a1.z = bf2f((ushort_t)(pv.w & 0xffff)) * s;
      a1.w = bf2f((ushort_t)(pv.w >> 16)) * s;
    }
    __builtin_nontemporal_store(a0, reinterpret_cast<f32x4*>(A_out + u * 8));
    __builtin_nontemporal_store(a1, reinterpret_cast<f32x4*>(A_out + u * 8 + 4));
  }
}

// ---------------- out = (opart0 + opart1) * (1/L) --------------------------
__global__ void reduce_out_kernel(const float* __restrict__ opart,
                                  const float* __restrict__ l_part,
                                  float* __restrict__ out)
{
  int i = blockIdx.x * 256 + threadIdx.x;
  const int n4 = BB * TT * HH / 4;
  if (i >= n4) return;
  const int row = i >> 5;                        // 32 float4 per row
  const float L = l_part[row] + l_part[BB * TT + row] +
                  l_part[2 * BB * TT + row] + l_part[3 * BB * TT + row];
  const float s = 1.0f / L;
  const float4* p0 = reinterpret_cast<const float4*>(opart);
  const float4* p1 = reinterpret_cast<const float4*>(opart + (long)BB * TT * HH);
  float4 a = p0[i], c = p1[i];
  a.x = (a.x + c.x) * s;
  a.y = (a.y + c.y) * s;
  a.z = (a.z + c.z) * s;
  a.w = (a.w + c.w) * s;
  *reinterpret_cast<float4*>(out + 4 * (long)i) = a;
}

__global__ void finalize_kernel(const float* __restrict__ ssq_part,
                                float* __restrict__ S_norm)
{
  int b = threadIdx.x;
  if (b < BB) {
    float s = 0.f;
    #pragma unroll
    for (int i = 0; i < 8; ++i) s += ssq_part[b * 8 + i];
    S_norm[b] = sqrtf(s);
  }
}

extern "C" void kernel_launch(void* const* d_in, const int* in_sizes, int n_in,
                              void* d_out, int out_size, void* d_ws, size_t ws_size,
                              hipStream_t stream)
{
  const float* node  = (const float*)d_in[0];
  const float* neigh = (const float*)d_in[1];
  const float* Wq = (const float*)d_in[4];
  const float* bq = (const float*)d_in[5];
  const float* Wk = (const float*)d_in[6];
  const float* bk = (const float*)d_in[7];
  const float* Wv = (const float*)d_in[8];
  const float* bv = (const float*)d_in[9];

  float* out    = (float*)d_out;
  float* A_out  = out + (long)BB * TT * HH;
  float* S_norm = A_out + (long)BB * TT * KEYS;

  ushort_t* q_hi = (ushort_t*)d_ws;                      // B*T*H
  ushort_t* q_lo = q_hi + (long)BB * TT * HH;
  ushort_t* k_hi = q_lo + (long)BB * TT * HH;            // B*KEYS*H
  ushort_t* k_lo = k_hi + (long)BB * KEYS * HH;
  ushort_t* v_t  = k_lo + (long)BB * KEYS * HH;          // B*H*KEYS
  ushort_t* wqh  = v_t + (long)BB * HH * KEYS;           // H*H x6
  ushort_t* wql  = wqh + HH * HH;
  ushort_t* wkh  = wql + HH * HH;
  ushort_t* wkl  = wkh + HH * HH;
  ushort_t* wvh  = wkl + HH * HH;
  ushort_t* wvl  = wvh + HH * HH;
  ushort_t* P_ws = wvl + HH * HH;                        // B*T*KEYS bf16
  float* l_part  = (float*)(P_ws + (long)BB * TT * KEYS);// 4*B*T
  float* ssq_part = l_part + 4 * BB * TT;                // 512
  float* opart   = ssq_part + 512;                       // 2*B*T*H

  prep_w_kernel<<<dim3((HH * HH + 255) / 256), dim3(256), 0, stream>>>(
      Wq, Wk, Wv, wqh, wql, wkh, wkl, wvh, wvl);
  proj_kernel<false><<<dim3(BB * TT / 64), dim3(256), 0, stream>>>(
      node, neigh, wqh, wql, bq, wvh, wvl, bv, q_hi, q_lo, v_t, 0);
  proj_kernel<true><<<dim3(BB * KEYS / 64), dim3(256), 0, stream>>>(
      node, neigh, wkh, wkl, bk, wvh, wvl, bv, k_hi, k_lo, v_t, 1);
  passX_kernel<<<dim3(BB * 8), dim3(256), 0, stream>>>(
      q_hi, q_lo, k_hi, k_lo, v_t, P_ws, l_part, ssq_part, opart);
  passY_kernel<<<dim3(4096), dim3(256), 0, stream>>>(P_ws, l_part, A_out);
  reduce_out_kernel<<<dim3((BB * TT * HH / 4 + 255) / 256), dim3(256), 0, stream>>>(
      opart, l_part, out);
  finalize_kernel<<<dim3(1), dim3(64), 0, stream>>>(ssq_part, S_norm);
}